// Round 20
// baseline (215.377 us; speedup 1.0000x reference)
//
#include <hip/hip_runtime.h>

// ============================================================================
// ExtraMHSA pipeline for MI355X (gfx950).  R25: R24 + full-tile double buffer
//   + vmcnt-free mid-step barrier (HK raw-s_barrier technique).
//
//   fused_attn step:  bar1(__syncthreads: drains prefetched tile) ->
//   issue stage(t+1 -> buf^1) -> score(buf) -> exp -> transpose ->
//   bar2(lgkmcnt(0)+raw s_barrier: T visible, t+1 loads STAY IN FLIGHT) ->
//   PV -> flip.  The t+1 loads drain at the NEXT bar1, covered by the whole
//   step (was: drained mid-step by the compiler's vmcnt(0)-before-barrier).
//   LDS: Rs[2 bufs][2 halves][128x128] 128KB + Ts 32KB = 160KB (AITER-size
//   blocks; occupancy already 1 block/CU at 98KB so this is free).
//
//   prep_all : LT pos embeds, BN-fold weights->bf16, ef tables, zero lbuf
//   front_k  : x ->(LDS) x1=silu(conv1) -> {q,k} or {v,p}  (R24 exact)
//   fused_attn: head1, <<<250, 512>>>, K=256, 10 steps, bf16 Opart
//   final2   : sep2a + sep2b + 5-partial bf16 reduce + output GEMMs (R24)
// ============================================================================

typedef unsigned short u16;
typedef __attribute__((ext_vector_type(8))) short bf16x8;   // 8 bf16 = 4 VGPRs
typedef __attribute__((ext_vector_type(4))) float f32x4;    // MFMA C/D frag
typedef __attribute__((ext_vector_type(4))) unsigned int u32x4;

#define HW 6400
#define BN_EPS 1e-5f

__device__ __forceinline__ u16 f2b(float f) {       // fp32 -> bf16 RNE
  unsigned u = __float_as_uint(f);
  u += 0x7fffu + ((u >> 16) & 1u);
  return (u16)(u >> 16);
}
__device__ __forceinline__ unsigned pack2(float a, float b) {
  return (unsigned)f2b(a) | ((unsigned)f2b(b) << 16);
}
__device__ __forceinline__ f32x4 MFMA(bf16x8 a, bf16x8 b, f32x4 c) {
  return __builtin_amdgcn_mfma_f32_16x16x32_bf16(a, b, c, 0, 0, 0);
}
__device__ __forceinline__ float silu_f(float y) {
  return y / (1.0f + __expf(-y));
}
__device__ __forceinline__ bf16x8 pack8(f32x4 lo, f32x4 hi, float sc) {
  union { bf16x8 v; uint4 u; } r;
  r.u.x = pack2(lo[0] * sc, lo[1] * sc);
  r.u.y = pack2(lo[2] * sc, lo[3] * sc);
  r.u.z = pack2(hi[0] * sc, hi[1] * sc);
  r.u.w = pack2(hi[2] * sc, hi[3] * sc);
  return r.v;
}
__device__ __forceinline__ void unpack8(bf16x8 v, f32x4& lo, f32x4& hi) {
  union { bf16x8 v; unsigned short e[8]; } u; u.v = v;
#pragma unroll
  for (int k = 0; k < 4; ++k) {
    lo[k] = __uint_as_float((unsigned)u.e[k] << 16);
    hi[k] = __uint_as_float((unsigned)u.e[k + 4] << 16);
  }
}
// async global->LDS, 16B per lane; dst is wave-uniform base (HW adds lane*16).
__device__ __forceinline__ void gload_lds16(const u16* src, u16* dst) {
  __builtin_amdgcn_global_load_lds(
      (const __attribute__((address_space(1))) void*)src,
      (__attribute__((address_space(3))) void*)dst, 16, 0, 0);
}
// vmcnt-free block barrier: drains this wave's LDS ops only (lgkmcnt), then
// raw s_barrier.  Global loads in flight are NOT drained (HK technique).
__device__ __forceinline__ void barrier_lgkm_only() {
  __builtin_amdgcn_sched_barrier(0);
  asm volatile("s_waitcnt lgkmcnt(0)" ::: "memory");
  __builtin_amdgcn_s_barrier();
  __builtin_amdgcn_sched_barrier(0);
}

// ---------------------------------------------------------------------------
// prep_all: [0,80) LT pos embeds; [80,144) weight BN-fold + ef tables;
//           [144,176) zero lbuf.
// ---------------------------------------------------------------------------
__global__ void prep_all(
    const float* __restrict__ rel_h, const float* __restrict__ rel_w,
    const float* __restrict__ ef_h, const float* __restrict__ ef_w,
    const float* __restrict__ w1, const float* __restrict__ g1, const float* __restrict__ b1,
    const float* __restrict__ m1, const float* __restrict__ v1,
    const float* __restrict__ w2, const float* __restrict__ g2, const float* __restrict__ b2,
    const float* __restrict__ m2, const float* __restrict__ v2,
    const float* __restrict__ w3, const float* __restrict__ g3, const float* __restrict__ b3,
    const float* __restrict__ m3, const float* __restrict__ v3,
    const float* __restrict__ wq, const float* __restrict__ bq,
    const float* __restrict__ wk, const float* __restrict__ bk,
    const float* __restrict__ wv, const float* __restrict__ bv,
    const float* __restrict__ wp, const float* __restrict__ bp,
    u16* __restrict__ LT,
    u16* __restrict__ w1b, float* __restrict__ b1e,
    u16* __restrict__ Wcat, float* __restrict__ bcat,
    u16* __restrict__ w2b, float* __restrict__ b2e,
    u16* __restrict__ w3b, float* __restrict__ b3e,
    u16* __restrict__ efhT, u16* __restrict__ efwT,
    u16* __restrict__ efhB, u16* __restrict__ efwB,
    float* __restrict__ lbuf)
{
  const int b = blockIdx.x;
  const int t = threadIdx.x;
  if (b < 80) {
    const int h = b;
    const int c0 = (t & 63) * 2;
    const float rh0 = rel_h[c0 * 80 + h], rh1 = rel_h[(c0 + 1) * 80 + h];
    for (int wcol = (t >> 6); wcol < 80; wcol += 4) {
      const int i = h * 80 + wcol;
      float rw0 = rel_w[c0 * 80 + wcol], rw1 = rel_w[(c0 + 1) * 80 + wcol];
      *(unsigned*)&LT[(size_t)i * 256 + 128 + c0] = pack2(rh0 + rw0, rh1 + rw1);
    }
  } else if (b < 144) {
    const int tid = (b - 80) * 256 + t;
    const int stride = 64 * 256;
    for (int idx = tid; idx < 128 * 256; idx += stride) {
      int o = idx >> 8;
      float s = g1[o] * rsqrtf(v1[o] + BN_EPS);
      w1b[idx] = f2b(w1[idx] * s);
    }
    for (int idx = tid; idx < 128; idx += stride) {
      float s = g1[idx] * rsqrtf(v1[idx] + BN_EPS);
      b1e[idx] = b1[idx] - m1[idx] * s;
    }
    for (int idx = tid; idx < 4 * 128 * 128; idx += stride) {
      int which = idx >> 14, r = idx & 16383;
      const float* src = which == 0 ? wq : which == 1 ? wk : which == 2 ? wv : wp;
      Wcat[idx] = f2b(src[r]);
    }
    for (int idx = tid; idx < 512; idx += stride) {
      int which = idx >> 7, r = idx & 127;
      const float* src = which == 0 ? bq : which == 1 ? bk : which == 2 ? bv : bp;
      bcat[idx] = src[r];
    }
    for (int idx = tid; idx < 256 * 128; idx += stride) {
      int o = idx >> 7;
      float s2 = g2[o] * rsqrtf(v2[o] + BN_EPS);
      w2b[idx] = f2b(w2[idx] * s2);
      float s3 = g3[o] * rsqrtf(v3[o] + BN_EPS);
      w3b[idx] = f2b(w3[idx] * s3);
    }
    for (int idx = tid; idx < 256; idx += stride) {
      float s2 = g2[idx] * rsqrtf(v2[idx] + BN_EPS);
      b2e[idx] = b2[idx] - m2[idx] * s2;
      float s3 = g3[idx] * rsqrtf(v3[idx] + BN_EPS);
      b3e[idx] = b3[idx] - m3[idx] * s3;
    }
    // ef tables: efhT/efwT [hj][c]; efhB/efwB [c][96] padded
    for (int idx = tid; idx < 80 * 128; idx += stride) {
      int hj = idx >> 7, c = idx & 127;
      efhT[idx] = f2b(ef_h[c * 80 + hj]);
      efwT[idx] = f2b(ef_w[c * 80 + hj]);
    }
    for (int idx = tid; idx < 128 * 96; idx += stride) {
      int c = idx / 96, hj = idx % 96;
      efhB[idx] = hj < 80 ? f2b(ef_h[c * 80 + hj]) : (u16)0;
      efwB[idx] = hj < 80 ? f2b(ef_w[c * 80 + hj]) : (u16)0;
    }
  } else {
    const int tid = (b - 144) * 256 + t;
    const int stride = 32 * 256;
    for (int idx = tid; idx < HW / 4; idx += stride)
      ((f32x4*)lbuf)[idx] = (f32x4){0.f, 0.f, 0.f, 0.f};
  }
}

// ---------------------------------------------------------------------------
// front_k: x ->(LDS) x1=silu(bn(conv1(x))) -> two projections.
// grid <<<800, 256>>>: bid<400 -> {q,k} (LT/RT), bid>=400 -> {v,p} (Vv/pT).
// ---------------------------------------------------------------------------
__global__ __launch_bounds__(256) void front_k(
    const float* __restrict__ x,
    const u16* __restrict__ w1b, const float* __restrict__ b1e,
    const u16* __restrict__ Wcat, const float* __restrict__ bcat,
    u16* __restrict__ LT, u16* __restrict__ RT, u16* __restrict__ Vv,
    u16* __restrict__ pT)
{
  __shared__ __align__(16) float xs[16][260];    // pad 260: <=2-way conflicts
  __shared__ __align__(16) u16 tr[16][136];
  const int t = threadIdx.x, lane = t & 63, w = t >> 6, jl = lane & 15, q = lane >> 4;
  const bool partA = blockIdx.x < 400;
  const int ib = partA ? blockIdx.x : blockIdx.x - 400;
  const int i0 = ib * 16;

#pragma unroll
  for (int pp = 0; pp < 4; ++pp) {
    const int p = w * 4 + pp;
    const int ch = p * 16 + (lane >> 2);
    const int ii = (lane & 3) * 4;
    f32x4 v = *(const f32x4*)(x + (size_t)ch * HW + i0 + ii);
    xs[ii][ch] = v[0]; xs[ii + 1][ch] = v[1];
    xs[ii + 2][ch] = v[2]; xs[ii + 3][ch] = v[3];
  }
  __syncthreads();

  bf16x8 afr[8];
#pragma unroll
  for (int ks = 0; ks < 8; ++ks) {
    f32x4 va = *(const f32x4*)&xs[jl][ks * 32 + q * 8];
    f32x4 vb = *(const f32x4*)&xs[jl][ks * 32 + q * 8 + 4];
    afr[ks] = pack8(va, vb, 1.0f);
  }
  f32x4 acc[2];
#pragma unroll
  for (int nn = 0; nn < 2; ++nn) acc[nn] = (f32x4){0.f, 0.f, 0.f, 0.f};
#pragma unroll
  for (int ks = 0; ks < 8; ++ks)
#pragma unroll
    for (int nn = 0; nn < 2; ++nn) {
      const int nf = w * 2 + nn;
      bf16x8 b = *(const bf16x8*)(w1b + (size_t)(nf * 16 + jl) * 256 + ks * 32 + q * 8);
      acc[nn] = MFMA(afr[ks], b, acc[nn]);
    }
#pragma unroll
  for (int nn = 0; nn < 2; ++nn) {
    const int c = (w * 2 + nn) * 16 + jl;
    const float bias = b1e[c];
#pragma unroll
    for (int r = 0; r < 4; ++r)
      tr[q * 4 + r][c] = f2b(silu_f(acc[nn][r] + bias));
  }
  __syncthreads();
  bf16x8 xa[4];
#pragma unroll
  for (int ks = 0; ks < 4; ++ks)
    xa[ks] = *(const bf16x8*)&tr[jl][ks * 32 + q * 8];

  for (int ncl = 0; ncl < 2; ++ncl) {
    const int nc = (partA ? 0 : 2) + ncl;
    f32x4 a2[2];
#pragma unroll
    for (int nn = 0; nn < 2; ++nn) a2[nn] = (f32x4){0.f, 0.f, 0.f, 0.f};
#pragma unroll
    for (int ks = 0; ks < 4; ++ks)
#pragma unroll
      for (int nn = 0; nn < 2; ++nn) {
        const int nf = w * 2 + nn;
        bf16x8 b = *(const bf16x8*)(Wcat + (size_t)(nc * 128 + nf * 16 + jl) * 128 + ks * 32 + q * 8);
        a2[nn] = MFMA(xa[ks], b, a2[nn]);
      }
    if (nc == 2) {                               // v: direct [c][i] store
#pragma unroll
      for (int nn = 0; nn < 2; ++nn) {
        const int c = (w * 2 + nn) * 16 + jl;
        const float bias = bcat[256 + c];
        uint2 pk;
        pk.x = pack2(a2[nn][0] + bias, a2[nn][1] + bias);
        pk.y = pack2(a2[nn][2] + bias, a2[nn][3] + bias);
        *(uint2*)(Vv + (size_t)c * HW + i0 + q * 4) = pk;
      }
    } else {
      __syncthreads();
#pragma unroll
      for (int nn = 0; nn < 2; ++nn) {
        const int c = (w * 2 + nn) * 16 + jl;
        const float bias = bcat[nc * 128 + c];
#pragma unroll
        for (int r = 0; r < 4; ++r)
          tr[q * 4 + r][c] = f2b(a2[nn][r] + bias);
      }
      __syncthreads();
#pragma unroll
      for (int rr = 0; rr < 4; ++rr) {
        const int r = w * 4 + rr;
        unsigned val = *(const unsigned*)&tr[r][lane * 2];
        const size_t row = (size_t)(i0 + r);
        if (nc == 0) {
          *(unsigned*)(LT + row * 256 + lane * 2) = val;
          *(unsigned*)(RT + row * 256 + 128 + lane * 2) = val;
        } else if (nc == 1) {
          *(unsigned*)(RT + row * 256 + lane * 2) = val;
        } else {
          *(unsigned*)(pT + row * 128 + lane * 2) = val;
        }
      }
    }
  }
}

// ---------------------------------------------------------------------------
// fused_attn: head1, grid <<<250, 512>>>.  8 waves = 2wi x 4wj, i-tile 128,
// mt=4, K=256; jp=bid/50, it=bid%50; 10 steps of 128 j.
// R25: full-tile double buffer Rs[2][2][128x128] (128KB) + Ts 32KB = 160KB.
// Step: bar1(__syncthreads, drains prefetched tile) -> issue stage(t+1 ->
// buf^1) -> score(buf) -> exp -> transpose -> bar2(lgkm-only raw s_barrier;
// t+1 loads stay in flight) -> PV -> flip.  Opart bf16 [row][p][c], p<5.
// ---------------------------------------------------------------------------
__global__ __launch_bounds__(512, 2) void fused_attn(
    const u16* __restrict__ LT,     // [HW][256]  L = [q | cp]
    const u16* __restrict__ RT,     // [HW][256]  R = [k | q]
    const u16* __restrict__ Vv,     // [128][HW]
    u16* __restrict__ Opart,        // [HW][5][128] bf16
    float* __restrict__ lv)         // [HW]
{
  __shared__ __align__(1024) u16 Rs[2][2][128 * 128];   // [buf][half] 128 KB
  __shared__ __align__(1024) u16 Ts[2][64 * 128];       // 32 KB
  const int t = threadIdx.x, lane = t & 63, w = t >> 6, jl = lane & 15, q = lane >> 4;
  const int bid = blockIdx.x;
  const int jp = bid / 50, it = bid % 50;        // 5 j-parts x 50 i-tiles
  const int wi = w & 1, wj = w >> 1;             // 2 i-groups x 4 j-quarters
  const int i0w = it * 128 + wi * 64;
  u16* Tw = Ts[wi];

  bf16x8 afr[4][8];
#pragma unroll
  for (int mt = 0; mt < 4; ++mt)
#pragma unroll
    for (int l = 0; l < 8; ++l)
      afr[mt][l] = *(const bf16x8*)(LT + (size_t)(i0w + mt * 16 + jl) * 256 + l * 32 + q * 8);

  f32x4 o[4][2];
#pragma unroll
  for (int mt = 0; mt < 4; ++mt)
#pragma unroll
    for (int cf = 0; cf < 2; ++cf) o[mt][cf] = (f32x4){0.f, 0.f, 0.f, 0.f};
  float lacc[4] = {0.f, 0.f, 0.f, 0.f};

  // stage a full 128x256 R-tile at column jj into buffer buf (8 gloads/wave)
  auto stage = [&](int jj, int buf) {
#pragma unroll
    for (int k = 0; k < 8; ++k) {
      const int b = k >> 2, cl = k & 3;
      const int cc = w * 4 + cl;
      const int jr = cc * 4 + (lane >> 4);
      const int cp = lane & 15;
      const int ch = (cp & ~7) | ((cp ^ jr) & 7);
      gload_lds16(RT + (size_t)(jj + jr) * 256 + b * 128 + ch * 8,
                  Rs[buf][b] + (cc << 9));
    }
  };

  stage(jp * 1280, 0);
  int cur = 0;

  for (int stp = 0; stp < 10; ++stp) {
    const int jj = jp * 1280 + stp * 128;

    f32x4 s[2][4];
#pragma unroll
    for (int nf = 0; nf < 2; ++nf)
#pragma unroll
      for (int mt = 0; mt < 4; ++mt) s[nf][mt] = (f32x4){0.f, 0.f, 0.f, 0.f};

    __syncthreads();                 // bar1: tile cur visible (vmcnt drained);
                                     //       prev PV's T reads done
    if (stp < 9) stage(jj + 128, cur ^ 1);   // issue next tile; drains at
                                             // NEXT bar1, covered by whole step

    // ---- score: S^T += R . L^T over both K-halves (reads Rs[cur])
#pragma unroll
    for (int h = 0; h < 2; ++h)
#pragma unroll
      for (int nf = 0; nf < 2; ++nf) {
        const int row = wj * 32 + nf * 16 + jl;
#pragma unroll
        for (int l = 0; l < 4; ++l) {
          const int ch = (l * 4 + q) ^ (jl & 7);
          bf16x8 b = *(const bf16x8*)(Rs[cur][h] + row * 128 + ch * 8);
          s[nf][0] = MFMA(b, afr[0][h * 4 + l], s[nf][0]);
          s[nf][1] = MFMA(b, afr[1][h * 4 + l], s[nf][1]);
          s[nf][2] = MFMA(b, afr[2][h * 4 + l], s[nf][2]);
          s[nf][3] = MFMA(b, afr[3][h * 4 + l], s[nf][3]);
        }
      }

    // ---- P = exp(S); rowsum partials
#pragma unroll
    for (int nf = 0; nf < 2; ++nf)
#pragma unroll
      for (int mt = 0; mt < 4; ++mt)
#pragma unroll
        for (int r = 0; r < 4; ++r) {
          float p = __expf(s[nf][mt][r]);
          s[nf][mt][r] = p;
          lacc[mt] += p;
        }

    // ---- transpose P -> T[wi], chunk-XOR swizzle
#pragma unroll
    for (int mt = 0; mt < 4; ++mt)
#pragma unroll
      for (int nf = 0; nf < 2; ++nf) {
        const int row = mt * 16 + jl;
        const int cs = (wj * 8 + nf * 4 + q) ^ ((jl & 7) << 2);
        uint2 pk;
        pk.x = pack2(s[nf][mt][0], s[nf][mt][1]);
        pk.y = pack2(s[nf][mt][2], s[nf][mt][3]);
        *(uint2*)(Tw + row * 128 + cs * 4) = pk;
      }
    barrier_lgkm_only();             // bar2: T visible; t+1 loads in flight

    // ---- PV: wave does [64 i][32 c] over full j (K=128)
#pragma unroll
    for (int ks2 = 0; ks2 < 4; ++ks2) {
      bf16x8 bv0 = *(const bf16x8*)(Vv + (size_t)(wj * 32 + jl) * HW + jj + ks2 * 32 + q * 8);
      bf16x8 bv1 = *(const bf16x8*)(Vv + (size_t)(wj * 32 + 16 + jl) * HW + jj + ks2 * 32 + q * 8);
      const int cb = (ks2 * 8 + q * 2) ^ ((jl & 7) << 2);
#pragma unroll
      for (int mt = 0; mt < 4; ++mt) {
        bf16x8 pa = *(const bf16x8*)(Tw + (mt * 16 + jl) * 128 + cb * 4);
        o[mt][0] = MFMA(pa, bv0, o[mt][0]);
        o[mt][1] = MFMA(pa, bv1, o[mt][1]);
      }
    }
    cur ^= 1;
  }

#pragma unroll
  for (int mt = 0; mt < 4; ++mt) {
    float rsum = lacc[mt];
    rsum += __shfl_xor(rsum, 16);
    rsum += __shfl_xor(rsum, 32);
    if (lane < 16)
      atomicAdd(&lv[i0w + mt * 16 + jl], rsum);
  }
#pragma unroll
  for (int mt = 0; mt < 4; ++mt) {
    const int ib = i0w + mt * 16 + q * 4;
#pragma unroll
    for (int cf = 0; cf < 2; ++cf) {
      const int c = wj * 32 + cf * 16 + jl;
#pragma unroll
      for (int r = 0; r < 4; ++r)
        Opart[((size_t)(ib + r) * 5 + jp) * 128 + c] = f2b(o[mt][cf][r]);
    }
  }
}

// ---------------------------------------------------------------------------
// final2: sep2a (A0) + sep2b (A2) + 5-partial bf16 red + final (R21 exact).
// grid <<<200, 512>>>: 32 rows/block, 8 waves = (rg row-group, ncl
// channel-quarter).  A0 by ncl==0 waves, A2 by ncl==1 waves (once per rg);
// Phase B all 8 waves, Opart rows L1-shared across ncl.
// ---------------------------------------------------------------------------
__global__ __launch_bounds__(512, 2) void final2(
    const u16* __restrict__ pT,        // [HW][128]
    const u16* __restrict__ efhT, const u16* __restrict__ efwT,   // [80][128]
    const u16* __restrict__ efhB, const u16* __restrict__ efwB,   // [128][96]
    const u16* __restrict__ Opart,     // [HW][5][128] bf16
    const float* __restrict__ lv,      // [HW]
    const u16* __restrict__ w2b, const float* __restrict__ b2e,
    const u16* __restrict__ w3b, const float* __restrict__ b3e,
    const float* __restrict__ x, float* __restrict__ outp)
{
  __shared__ __align__(16) u16 eAs[32][104];
  __shared__ __align__(16) u16 eBs[32][104];
  __shared__ float sAL[32], sBL[32];
  __shared__ __align__(16) u16 T2[32][136];
  const int t = threadIdx.x, lane = t & 63, w = t >> 6, jl = lane & 15, q = lane >> 4;
  const int rg = w & 1, ncl = w >> 1;
  const int i0 = blockIdx.x * 32;
  const int rowA = i0 + rg * 16 + jl;
  const int iloc = rg * 16 + jl;

  // ---- Phase A0: sep2a, once per row-group (ncl==0 waves)
  if (ncl == 0) {
    bf16x8 pfr[4];
#pragma unroll
    for (int l = 0; l < 4; ++l)
      pfr[l] = *(const bf16x8*)(pT + (size_t)rowA * 128 + l * 32 + q * 8);
    f32x4 sa[5], sb[5];
#pragma unroll
    for (int nf = 0; nf < 5; ++nf) {
      sa[nf] = (f32x4){0.f, 0.f, 0.f, 0.f};
      sb[nf] = (f32x4){0.f, 0.f, 0.f, 0.f};
    }
#pragma unroll
    for (int nf = 0; nf < 5; ++nf) {
      const int row = nf * 16 + jl;              // hj row, < 80
#pragma unroll
      for (int l = 0; l < 4; ++l) {
        bf16x8 eh = *(const bf16x8*)(efhT + (size_t)row * 128 + l * 32 + q * 8);
        bf16x8 ew = *(const bf16x8*)(efwT + (size_t)row * 128 + l * 32 + q * 8);
        sa[nf] = MFMA(eh, pfr[l], sa[nf]);
        sb[nf] = MFMA(ew, pfr[l], sb[nf]);
      }
    }
    float ra = 0.f, rb = 0.f;
#pragma unroll
    for (int nf = 0; nf < 5; ++nf) {
      float ea[4], eb[4];
#pragma unroll
      for (int r = 0; r < 4; ++r) {
        ea[r] = __expf(sa[nf][r]); ra += ea[r];
        eb[r] = __expf(sb[nf][r]); rb += eb[r];
      }
      uint2 pa, pb;
      pa.x = pack2(ea[0], ea[1]); pa.y = pack2(ea[2], ea[3]);
      pb.x = pack2(eb[0], eb[1]); pb.y = pack2(eb[2], eb[3]);
      *(uint2*)&eAs[iloc][nf * 16 + q * 4] = pa;
      *(uint2*)&eBs[iloc][nf * 16 + q * 4] = pb;
    }
    *(uint2*)&eAs[iloc][80 + q * 4] = (uint2){0u, 0u};
    *(uint2*)&eBs[iloc][80 + q * 4] = (uint2){0u, 0u};
    ra += __shfl_xor(ra, 16); ra += __shfl_xor(ra, 32);
    rb += __shfl_xor(rb, 16); rb += __shfl_xor(rb, 32);
    if (lane < 16) { sAL[iloc] = ra; sBL[iloc] = rb; }
  }
  __syncthreads();

  // ---- Phase A2: sep2b -> T2, once per row-group (ncl==1 waves)
  if (ncl == 1) {
    bf16x8 fa[3], fb[3];
#pragma unroll
    for (int l = 0; l < 3; ++l) {
      fa[l] = *(const bf16x8*)&eAs[iloc][l * 32 + q * 8];
      fb[l] = *(const bf16x8*)&eBs[iloc][l * 32 + q * 8];
    }
    f32x4 oU[8], oW[8];
#pragma unroll
    for (int nf = 0; nf < 8; ++nf) {
      oU[nf] = (f32x4){0.f, 0.f, 0.f, 0.f};
      oW[nf] = (f32x4){0.f, 0.f, 0.f, 0.f};
    }
#pragma unroll
    for (int l = 0; l < 3; ++l)
#pragma unroll
      for (int nf = 0; nf < 8; ++nf) {
        bf16x8 bh = *(const bf16x8*)(efhB + (size_t)(nf * 16 + jl) * 96 + l * 32 + q * 8);
        bf16x8 bw = *(const bf16x8*)(efwB + (size_t)(nf * 16 + jl) * 96 + l * 32 + q * 8);
        oU[nf] = MFMA(fa[l], bh, oU[nf]);
        oW[nf] = MFMA(fb[l], bw, oW[nf]);
      }
    float ia[4], iw[4];
#pragma unroll
    for (int r = 0; r < 4; ++r) {
      ia[r] = 1.0f / sAL[rg * 16 + q * 4 + r];
      iw[r] = 1.0f / sBL[rg * 16 + q * 4 + r];
    }
#pragma unroll
    for (int nf = 0; nf < 8; ++nf)
#pragma unroll
      for (int r = 0; r < 4; ++r)
        T2[rg * 16 + q * 4 + r][nf * 16 + jl] =
            f2b(oU[nf][r] * ia[r] + oW[nf][r] * iw[r]);
  }
  __syncthreads();

  // ---- Phase B: red (5 bf16 partials, contiguous) + output GEMMs
  const float inv1 = 1.0f / lv[rowA];
  const u16* OrBase = Opart + (size_t)rowA * 5 * 128;
  f32x4 a1[4], a2[4];
#pragma unroll
  for (int nf = 0; nf < 4; ++nf) {
    a1[nf] = (f32x4){0.f, 0.f, 0.f, 0.f};
    a2[nf] = (f32x4){0.f, 0.f, 0.f, 0.f};
  }
#pragma unroll
  for (int ks = 0; ks < 4; ++ks) {
    f32x4 s1a = (f32x4){0.f, 0.f, 0.f, 0.f};
    f32x4 s1b = (f32x4){0.f, 0.f, 0.f, 0.f};
#pragma unroll
    for (int p = 0; p < 5; ++p) {
      bf16x8 pv = *(const bf16x8*)(OrBase + p * 128 + ks * 32 + q * 8);
      f32x4 lo, hi;
      unpack8(pv, lo, hi);
      s1a += lo;
      s1b += hi;
    }
    bf16x8 fa1 = pack8(s1a, s1b, inv1);
    bf16x8 fa2 = *(const bf16x8*)&T2[rg * 16 + jl][ks * 32 + q * 8];
#pragma unroll
    for (int nf = 0; nf < 4; ++nf) {
      const int d = ncl * 64 + nf * 16 + jl;
      bf16x8 b2f = *(const bf16x8*)(w2b + (size_t)d * 128 + ks * 32 + q * 8);
      bf16x8 b3f = *(const bf16x8*)(w3b + (size_t)d * 128 + ks * 32 + q * 8);
      a1[nf] = MFMA(fa1, b2f, a1[nf]);
      a2[nf] = MFMA(fa2, b3f, a2[nf]);
    }
  }
#pragma unroll
  for (int nf = 0; nf < 4; ++nf) {
    const int d = ncl * 64 + nf * 16 + jl;
    const float bb2 = b2e[d], bb3 = b3e[d];
    const size_t base = (size_t)d * HW + i0 + rg * 16 + q * 4;
    f32x4 xv = *(const f32x4*)(x + base);
    f32x4 rv;
#pragma unroll
    for (int r = 0; r < 4; ++r)
      rv[r] = xv[r] + silu_f(a1[nf][r] + bb2) + silu_f(a2[nf][r] + bb3);
    *(f32x4*)(outp + base) = rv;
  }
}

// ---------------------------------------------------------------------------
extern "C" void kernel_launch(void* const* d_in, const int* in_sizes, int n_in,
                              void* d_out, int out_size, void* d_ws, size_t ws_size,
                              hipStream_t stream)
{
  (void)in_sizes; (void)n_in; (void)out_size; (void)ws_size;
  const float* x   = (const float*)d_in[0];
  const float* w1  = (const float*)d_in[1];
  const float* g1  = (const float*)d_in[2];
  const float* b1  = (const float*)d_in[3];
  const float* m1  = (const float*)d_in[4];
  const float* v1  = (const float*)d_in[5];
  const float* w2  = (const float*)d_in[6];
  const float* g2  = (const float*)d_in[7];
  const float* b2  = (const float*)d_in[8];
  const float* m2  = (const float*)d_in[9];
  const float* v2  = (const float*)d_in[10];
  const float* w3  = (const float*)d_in[11];
  const float* g3  = (const float*)d_in[12];
  const float* b3  = (const float*)d_in[13];
  const float* m3  = (const float*)d_in[14];
  const float* v3  = (const float*)d_in[15];
  const float* wq  = (const float*)d_in[16];
  const float* bq  = (const float*)d_in[17];
  const float* wk  = (const float*)d_in[18];
  const float* bk  = (const float*)d_in[19];
  const float* wv  = (const float*)d_in[20];
  const float* bv  = (const float*)d_in[21];
  const float* wp  = (const float*)d_in[22];
  const float* bp  = (const float*)d_in[23];
  const float* rel_h = (const float*)d_in[24];
  const float* rel_w = (const float*)d_in[25];
  const float* ef_h  = (const float*)d_in[26];
  const float* ef_w  = (const float*)d_in[27];
  float* outp = (float*)d_out;

  char* ws = (char*)d_ws;
  size_t off = 0;
  auto alloc = [&](size_t bytes) -> void* {
    void* p = ws + off;
    off += (bytes + 511) & ~(size_t)511;
    return p;
  };
  u16* LT    = (u16*)alloc((size_t)HW * 256 * 2);
  u16* RT    = (u16*)alloc((size_t)HW * 256 * 2);
  u16* pT    = (u16*)alloc((size_t)HW * 128 * 2);
  u16* Vv    = (u16*)alloc((size_t)HW * 128 * 2);
  u16* Opart = (u16*)alloc((size_t)HW * 5 * 128 * 2);      // 8.2 MB bf16
  float* lbuf  = (float*)alloc((size_t)HW * 4);
  u16* w1b   = (u16*)alloc(128 * 256 * 2);
  float* b1e = (float*)alloc(128 * 4);
  u16* Wcat  = (u16*)alloc(512 * 128 * 2);
  float* bcat = (float*)alloc(512 * 4);
  u16* w2b   = (u16*)alloc(256 * 128 * 2);
  float* b2e = (float*)alloc(256 * 4);
  u16* w3b   = (u16*)alloc(256 * 128 * 2);
  float* b3e = (float*)alloc(256 * 4);
  u16* efhT  = (u16*)alloc(80 * 128 * 2);
  u16* efwT  = (u16*)alloc(80 * 128 * 2);
  u16* efhB  = (u16*)alloc(128 * 96 * 2);
  u16* efwB  = (u16*)alloc(128 * 96 * 2);

  prep_all<<<176, 256, 0, stream>>>(rel_h, rel_w, ef_h, ef_w,
                                    w1, g1, b1, m1, v1, w2, g2, b2, m2, v2,
                                    w3, g3, b3, m3, v3, wq, bq, wk, bk, wv, bv, wp, bp,
                                    LT, w1b, b1e, Wcat, bcat, w2b, b2e, w3b, b3e,
                                    efhT, efwT, efhB, efwB, lbuf);
  front_k<<<800, 256, 0, stream>>>(x, w1b, b1e, Wcat, bcat, LT, RT, Vv, pT);
  fused_attn<<<250, 512, 0, stream>>>(LT, RT, Vv, Opart, lbuf);
  final2<<<dim3(200), 512, 0, stream>>>(pT, efhT, efwT, efhB, efwB,
                                        Opart, lbuf, w2b, b2e, w3b, b3e,
                                        x, outp);
}

// Round 21
// 212.059 us; speedup vs baseline: 1.0156x; 1.0156x over previous
//
#include <hip/hip_runtime.h>

// ============================================================================
// ExtraMHSA pipeline for MI355X (gfx950).  R26: revert to R24 (best measured,
//   214.2us total; fused_attn 60.5us reproduced in R22/R24).
//
//   R25 falsified the vmcnt-drain theory: full-tile double buffer + lgkm-only
//   mid-step barrier regressed to 62us (extra LDS/VGPR cost, no drain win).
//   The residual stall is the lockstep 8-wave 2-waves/SIMD serialization --
//   structural at HIP source level (R7/R12/R14/R15/R18/R21/R25 all null or
//   negative around this point).
//
//   prep_all : LT pos embeds, BN-fold weights->bf16, ef tables, zero lbuf
//   front_k  : x ->(LDS) x1=silu(conv1) -> {q,k} or {v,p}
//   fused_attn: head1, <<<250, 512>>>, K=256, 10 steps, 2-barrier step,
//              bf16 Opart [row][p][c]
//   final2   : sep2a + sep2b + 5-partial bf16 reduce + output GEMMs
// ============================================================================

typedef unsigned short u16;
typedef __attribute__((ext_vector_type(8))) short bf16x8;   // 8 bf16 = 4 VGPRs
typedef __attribute__((ext_vector_type(4))) float f32x4;    // MFMA C/D frag
typedef __attribute__((ext_vector_type(4))) unsigned int u32x4;

#define HW 6400
#define BN_EPS 1e-5f

__device__ __forceinline__ u16 f2b(float f) {       // fp32 -> bf16 RNE
  unsigned u = __float_as_uint(f);
  u += 0x7fffu + ((u >> 16) & 1u);
  return (u16)(u >> 16);
}
__device__ __forceinline__ unsigned pack2(float a, float b) {
  return (unsigned)f2b(a) | ((unsigned)f2b(b) << 16);
}
__device__ __forceinline__ f32x4 MFMA(bf16x8 a, bf16x8 b, f32x4 c) {
  return __builtin_amdgcn_mfma_f32_16x16x32_bf16(a, b, c, 0, 0, 0);
}
__device__ __forceinline__ float silu_f(float y) {
  return y / (1.0f + __expf(-y));
}
__device__ __forceinline__ bf16x8 pack8(f32x4 lo, f32x4 hi, float sc) {
  union { bf16x8 v; uint4 u; } r;
  r.u.x = pack2(lo[0] * sc, lo[1] * sc);
  r.u.y = pack2(lo[2] * sc, lo[3] * sc);
  r.u.z = pack2(hi[0] * sc, hi[1] * sc);
  r.u.w = pack2(hi[2] * sc, hi[3] * sc);
  return r.v;
}
__device__ __forceinline__ void unpack8(bf16x8 v, f32x4& lo, f32x4& hi) {
  union { bf16x8 v; unsigned short e[8]; } u; u.v = v;
#pragma unroll
  for (int k = 0; k < 4; ++k) {
    lo[k] = __uint_as_float((unsigned)u.e[k] << 16);
    hi[k] = __uint_as_float((unsigned)u.e[k + 4] << 16);
  }
}
// async global->LDS, 16B per lane; dst is wave-uniform base (HW adds lane*16).
__device__ __forceinline__ void gload_lds16(const u16* src, u16* dst) {
  __builtin_amdgcn_global_load_lds(
      (const __attribute__((address_space(1))) void*)src,
      (__attribute__((address_space(3))) void*)dst, 16, 0, 0);
}

// ---------------------------------------------------------------------------
// prep_all: [0,80) LT pos embeds; [80,144) weight BN-fold + ef tables;
//           [144,176) zero lbuf.
// ---------------------------------------------------------------------------
__global__ void prep_all(
    const float* __restrict__ rel_h, const float* __restrict__ rel_w,
    const float* __restrict__ ef_h, const float* __restrict__ ef_w,
    const float* __restrict__ w1, const float* __restrict__ g1, const float* __restrict__ b1,
    const float* __restrict__ m1, const float* __restrict__ v1,
    const float* __restrict__ w2, const float* __restrict__ g2, const float* __restrict__ b2,
    const float* __restrict__ m2, const float* __restrict__ v2,
    const float* __restrict__ w3, const float* __restrict__ g3, const float* __restrict__ b3,
    const float* __restrict__ m3, const float* __restrict__ v3,
    const float* __restrict__ wq, const float* __restrict__ bq,
    const float* __restrict__ wk, const float* __restrict__ bk,
    const float* __restrict__ wv, const float* __restrict__ bv,
    const float* __restrict__ wp, const float* __restrict__ bp,
    u16* __restrict__ LT,
    u16* __restrict__ w1b, float* __restrict__ b1e,
    u16* __restrict__ Wcat, float* __restrict__ bcat,
    u16* __restrict__ w2b, float* __restrict__ b2e,
    u16* __restrict__ w3b, float* __restrict__ b3e,
    u16* __restrict__ efhT, u16* __restrict__ efwT,
    u16* __restrict__ efhB, u16* __restrict__ efwB,
    float* __restrict__ lbuf)
{
  const int b = blockIdx.x;
  const int t = threadIdx.x;
  if (b < 80) {
    const int h = b;
    const int c0 = (t & 63) * 2;
    const float rh0 = rel_h[c0 * 80 + h], rh1 = rel_h[(c0 + 1) * 80 + h];
    for (int wcol = (t >> 6); wcol < 80; wcol += 4) {
      const int i = h * 80 + wcol;
      float rw0 = rel_w[c0 * 80 + wcol], rw1 = rel_w[(c0 + 1) * 80 + wcol];
      *(unsigned*)&LT[(size_t)i * 256 + 128 + c0] = pack2(rh0 + rw0, rh1 + rw1);
    }
  } else if (b < 144) {
    const int tid = (b - 80) * 256 + t;
    const int stride = 64 * 256;
    for (int idx = tid; idx < 128 * 256; idx += stride) {
      int o = idx >> 8;
      float s = g1[o] * rsqrtf(v1[o] + BN_EPS);
      w1b[idx] = f2b(w1[idx] * s);
    }
    for (int idx = tid; idx < 128; idx += stride) {
      float s = g1[idx] * rsqrtf(v1[idx] + BN_EPS);
      b1e[idx] = b1[idx] - m1[idx] * s;
    }
    for (int idx = tid; idx < 4 * 128 * 128; idx += stride) {
      int which = idx >> 14, r = idx & 16383;
      const float* src = which == 0 ? wq : which == 1 ? wk : which == 2 ? wv : wp;
      Wcat[idx] = f2b(src[r]);
    }
    for (int idx = tid; idx < 512; idx += stride) {
      int which = idx >> 7, r = idx & 127;
      const float* src = which == 0 ? bq : which == 1 ? bk : which == 2 ? bv : bp;
      bcat[idx] = src[r];
    }
    for (int idx = tid; idx < 256 * 128; idx += stride) {
      int o = idx >> 7;
      float s2 = g2[o] * rsqrtf(v2[o] + BN_EPS);
      w2b[idx] = f2b(w2[idx] * s2);
      float s3 = g3[o] * rsqrtf(v3[o] + BN_EPS);
      w3b[idx] = f2b(w3[idx] * s3);
    }
    for (int idx = tid; idx < 256; idx += stride) {
      float s2 = g2[idx] * rsqrtf(v2[idx] + BN_EPS);
      b2e[idx] = b2[idx] - m2[idx] * s2;
      float s3 = g3[idx] * rsqrtf(v3[idx] + BN_EPS);
      b3e[idx] = b3[idx] - m3[idx] * s3;
    }
    // ef tables: efhT/efwT [hj][c]; efhB/efwB [c][96] padded
    for (int idx = tid; idx < 80 * 128; idx += stride) {
      int hj = idx >> 7, c = idx & 127;
      efhT[idx] = f2b(ef_h[c * 80 + hj]);
      efwT[idx] = f2b(ef_w[c * 80 + hj]);
    }
    for (int idx = tid; idx < 128 * 96; idx += stride) {
      int c = idx / 96, hj = idx % 96;
      efhB[idx] = hj < 80 ? f2b(ef_h[c * 80 + hj]) : (u16)0;
      efwB[idx] = hj < 80 ? f2b(ef_w[c * 80 + hj]) : (u16)0;
    }
  } else {
    const int tid = (b - 144) * 256 + t;
    const int stride = 32 * 256;
    for (int idx = tid; idx < HW / 4; idx += stride)
      ((f32x4*)lbuf)[idx] = (f32x4){0.f, 0.f, 0.f, 0.f};
  }
}

// ---------------------------------------------------------------------------
// front_k: x ->(LDS) x1=silu(bn(conv1(x))) -> two projections.
// grid <<<800, 256>>>: bid<400 -> {q,k} (LT/RT), bid>=400 -> {v,p} (Vv/pT).
// ---------------------------------------------------------------------------
__global__ __launch_bounds__(256) void front_k(
    const float* __restrict__ x,
    const u16* __restrict__ w1b, const float* __restrict__ b1e,
    const u16* __restrict__ Wcat, const float* __restrict__ bcat,
    u16* __restrict__ LT, u16* __restrict__ RT, u16* __restrict__ Vv,
    u16* __restrict__ pT)
{
  __shared__ __align__(16) float xs[16][260];    // pad 260: <=2-way conflicts
  __shared__ __align__(16) u16 tr[16][136];
  const int t = threadIdx.x, lane = t & 63, w = t >> 6, jl = lane & 15, q = lane >> 4;
  const bool partA = blockIdx.x < 400;
  const int ib = partA ? blockIdx.x : blockIdx.x - 400;
  const int i0 = ib * 16;

#pragma unroll
  for (int pp = 0; pp < 4; ++pp) {
    const int p = w * 4 + pp;
    const int ch = p * 16 + (lane >> 2);
    const int ii = (lane & 3) * 4;
    f32x4 v = *(const f32x4*)(x + (size_t)ch * HW + i0 + ii);
    xs[ii][ch] = v[0]; xs[ii + 1][ch] = v[1];
    xs[ii + 2][ch] = v[2]; xs[ii + 3][ch] = v[3];
  }
  __syncthreads();

  bf16x8 afr[8];
#pragma unroll
  for (int ks = 0; ks < 8; ++ks) {
    f32x4 va = *(const f32x4*)&xs[jl][ks * 32 + q * 8];
    f32x4 vb = *(const f32x4*)&xs[jl][ks * 32 + q * 8 + 4];
    afr[ks] = pack8(va, vb, 1.0f);
  }
  f32x4 acc[2];
#pragma unroll
  for (int nn = 0; nn < 2; ++nn) acc[nn] = (f32x4){0.f, 0.f, 0.f, 0.f};
#pragma unroll
  for (int ks = 0; ks < 8; ++ks)
#pragma unroll
    for (int nn = 0; nn < 2; ++nn) {
      const int nf = w * 2 + nn;
      bf16x8 b = *(const bf16x8*)(w1b + (size_t)(nf * 16 + jl) * 256 + ks * 32 + q * 8);
      acc[nn] = MFMA(afr[ks], b, acc[nn]);
    }
#pragma unroll
  for (int nn = 0; nn < 2; ++nn) {
    const int c = (w * 2 + nn) * 16 + jl;
    const float bias = b1e[c];
#pragma unroll
    for (int r = 0; r < 4; ++r)
      tr[q * 4 + r][c] = f2b(silu_f(acc[nn][r] + bias));
  }
  __syncthreads();
  bf16x8 xa[4];
#pragma unroll
  for (int ks = 0; ks < 4; ++ks)
    xa[ks] = *(const bf16x8*)&tr[jl][ks * 32 + q * 8];

  for (int ncl = 0; ncl < 2; ++ncl) {
    const int nc = (partA ? 0 : 2) + ncl;
    f32x4 a2[2];
#pragma unroll
    for (int nn = 0; nn < 2; ++nn) a2[nn] = (f32x4){0.f, 0.f, 0.f, 0.f};
#pragma unroll
    for (int ks = 0; ks < 4; ++ks)
#pragma unroll
      for (int nn = 0; nn < 2; ++nn) {
        const int nf = w * 2 + nn;
        bf16x8 b = *(const bf16x8*)(Wcat + (size_t)(nc * 128 + nf * 16 + jl) * 128 + ks * 32 + q * 8);
        a2[nn] = MFMA(xa[ks], b, a2[nn]);
      }
    if (nc == 2) {                               // v: direct [c][i] store
#pragma unroll
      for (int nn = 0; nn < 2; ++nn) {
        const int c = (w * 2 + nn) * 16 + jl;
        const float bias = bcat[256 + c];
        uint2 pk;
        pk.x = pack2(a2[nn][0] + bias, a2[nn][1] + bias);
        pk.y = pack2(a2[nn][2] + bias, a2[nn][3] + bias);
        *(uint2*)(Vv + (size_t)c * HW + i0 + q * 4) = pk;
      }
    } else {
      __syncthreads();
#pragma unroll
      for (int nn = 0; nn < 2; ++nn) {
        const int c = (w * 2 + nn) * 16 + jl;
        const float bias = bcat[nc * 128 + c];
#pragma unroll
        for (int r = 0; r < 4; ++r)
          tr[q * 4 + r][c] = f2b(a2[nn][r] + bias);
      }
      __syncthreads();
#pragma unroll
      for (int rr = 0; rr < 4; ++rr) {
        const int r = w * 4 + rr;
        unsigned val = *(const unsigned*)&tr[r][lane * 2];
        const size_t row = (size_t)(i0 + r);
        if (nc == 0) {
          *(unsigned*)(LT + row * 256 + lane * 2) = val;
          *(unsigned*)(RT + row * 256 + 128 + lane * 2) = val;
        } else if (nc == 1) {
          *(unsigned*)(RT + row * 256 + lane * 2) = val;
        } else {
          *(unsigned*)(pT + row * 128 + lane * 2) = val;
        }
      }
    }
  }
}

// ---------------------------------------------------------------------------
// fused_attn: head1, grid <<<250, 512>>>.  8 waves = 2wi x 4wj, i-tile 128,
// mt=4, K=256; jp=bid/50, it=bid%50; 10 steps of 128 j.
// 2 barriers/step -- bar1; score; exp; transpose; bar2(Rs done + T visible);
// stage-next; PV.  Stage drains at next bar1 under all of PV.
// LDS: Rs[2] 64KB, Ts 32KB.  Opart bf16 [row][p][c], p<5.
// ---------------------------------------------------------------------------
__global__ __launch_bounds__(512, 2) void fused_attn(
    const u16* __restrict__ LT,     // [HW][256]  L = [q | cp]
    const u16* __restrict__ RT,     // [HW][256]  R = [k | q]
    const u16* __restrict__ Vv,     // [128][HW]
    u16* __restrict__ Opart,        // [HW][5][128] bf16
    float* __restrict__ lv)         // [HW]
{
  __shared__ __align__(1024) u16 Rs[2][128 * 128];
  __shared__ __align__(1024) u16 Ts[2][64 * 128];
  const int t = threadIdx.x, lane = t & 63, w = t >> 6, jl = lane & 15, q = lane >> 4;
  const int bid = blockIdx.x;
  const int jp = bid / 50, it = bid % 50;        // 5 j-parts x 50 i-tiles
  const int wi = w & 1, wj = w >> 1;             // 2 i-groups x 4 j-quarters
  const int i0w = it * 128 + wi * 64;
  u16* Tw = Ts[wi];

  bf16x8 afr[4][8];
#pragma unroll
  for (int mt = 0; mt < 4; ++mt)
#pragma unroll
    for (int l = 0; l < 8; ++l)
      afr[mt][l] = *(const bf16x8*)(LT + (size_t)(i0w + mt * 16 + jl) * 256 + l * 32 + q * 8);

  f32x4 o[4][2];
#pragma unroll
  for (int mt = 0; mt < 4; ++mt)
#pragma unroll
    for (int cf = 0; cf < 2; ++cf) o[mt][cf] = (f32x4){0.f, 0.f, 0.f, 0.f};
  float lacc[4] = {0.f, 0.f, 0.f, 0.f};

  auto stage = [&](int jj) {
#pragma unroll
    for (int k = 0; k < 8; ++k) {
      const int b = k >> 2, cl = k & 3;
      const int cc = w * 4 + cl;
      const int jr = cc * 4 + (lane >> 4);
      const int cp = lane & 15;
      const int ch = (cp & ~7) | ((cp ^ jr) & 7);
      gload_lds16(RT + (size_t)(jj + jr) * 256 + b * 128 + ch * 8,
                  Rs[b] + (cc << 9));
    }
  };

  stage(jp * 1280);

  for (int stp = 0; stp < 10; ++stp) {
    const int jj = jp * 1280 + stp * 128;

    f32x4 s[2][4];
#pragma unroll
    for (int nf = 0; nf < 2; ++nf)
#pragma unroll
      for (int mt = 0; mt < 4; ++mt) s[nf][mt] = (f32x4){0.f, 0.f, 0.f, 0.f};

    __syncthreads();                             // bar1: staged visible; prev PV's T reads done

    // ---- score: S^T += R . L^T over both K-halves
#pragma unroll
    for (int h = 0; h < 2; ++h)
#pragma unroll
      for (int nf = 0; nf < 2; ++nf) {
        const int row = wj * 32 + nf * 16 + jl;
#pragma unroll
        for (int l = 0; l < 4; ++l) {
          const int ch = (l * 4 + q) ^ (jl & 7);
          bf16x8 b = *(const bf16x8*)(Rs[h] + row * 128 + ch * 8);
          s[nf][0] = MFMA(b, afr[0][h * 4 + l], s[nf][0]);
          s[nf][1] = MFMA(b, afr[1][h * 4 + l], s[nf][1]);
          s[nf][2] = MFMA(b, afr[2][h * 4 + l], s[nf][2]);
          s[nf][3] = MFMA(b, afr[3][h * 4 + l], s[nf][3]);
        }
      }

    // ---- P = exp(S); rowsum partials (regs + Tw only; Rs untouched)
#pragma unroll
    for (int nf = 0; nf < 2; ++nf)
#pragma unroll
      for (int mt = 0; mt < 4; ++mt)
#pragma unroll
        for (int r = 0; r < 4; ++r) {
          float p = __expf(s[nf][mt][r]);
          s[nf][mt][r] = p;
          lacc[mt] += p;
        }

    // ---- transpose P -> T[wi], chunk-XOR swizzle
#pragma unroll
    for (int mt = 0; mt < 4; ++mt)
#pragma unroll
      for (int nf = 0; nf < 2; ++nf) {
        const int row = mt * 16 + jl;
        const int cs = (wj * 8 + nf * 4 + q) ^ ((jl & 7) << 2);
        uint2 pk;
        pk.x = pack2(s[nf][mt][0], s[nf][mt][1]);
        pk.y = pack2(s[nf][mt][2], s[nf][mt][3]);
        *(uint2*)(Tw + row * 128 + cs * 4) = pk;
      }
    __syncthreads();                             // bar2: Rs reads done + T visible
    if (stp < 9) stage(jj + 128);                // drains at next bar1, under PV

    // ---- PV: wave does [64 i][32 c] over full j (K=128)
#pragma unroll
    for (int ks2 = 0; ks2 < 4; ++ks2) {
      bf16x8 bv0 = *(const bf16x8*)(Vv + (size_t)(wj * 32 + jl) * HW + jj + ks2 * 32 + q * 8);
      bf16x8 bv1 = *(const bf16x8*)(Vv + (size_t)(wj * 32 + 16 + jl) * HW + jj + ks2 * 32 + q * 8);
      const int cb = (ks2 * 8 + q * 2) ^ ((jl & 7) << 2);
#pragma unroll
      for (int mt = 0; mt < 4; ++mt) {
        bf16x8 pa = *(const bf16x8*)(Tw + (mt * 16 + jl) * 128 + cb * 4);
        o[mt][0] = MFMA(pa, bv0, o[mt][0]);
        o[mt][1] = MFMA(pa, bv1, o[mt][1]);
      }
    }
  }

#pragma unroll
  for (int mt = 0; mt < 4; ++mt) {
    float rsum = lacc[mt];
    rsum += __shfl_xor(rsum, 16);
    rsum += __shfl_xor(rsum, 32);
    if (lane < 16)
      atomicAdd(&lv[i0w + mt * 16 + jl], rsum);
  }
#pragma unroll
  for (int mt = 0; mt < 4; ++mt) {
    const int ib = i0w + mt * 16 + q * 4;
#pragma unroll
    for (int cf = 0; cf < 2; ++cf) {
      const int c = wj * 32 + cf * 16 + jl;
#pragma unroll
      for (int r = 0; r < 4; ++r)
        Opart[((size_t)(ib + r) * 5 + jp) * 128 + c] = f2b(o[mt][cf][r]);
    }
  }
}

// ---------------------------------------------------------------------------
// final2: sep2a (A0) + sep2b (A2) + 5-partial bf16 red + final (R21 exact).
// grid <<<200, 512>>>: 32 rows/block, 8 waves = (rg row-group, ncl
// channel-quarter).  A0 by ncl==0 waves, A2 by ncl==1 waves (once per rg);
// Phase B all 8 waves, Opart rows L1-shared across ncl.
// ---------------------------------------------------------------------------
__global__ __launch_bounds__(512, 2) void final2(
    const u16* __restrict__ pT,        // [HW][128]
    const u16* __restrict__ efhT, const u16* __restrict__ efwT,   // [80][128]
    const u16* __restrict__ efhB, const u16* __restrict__ efwB,   // [128][96]
    const u16* __restrict__ Opart,     // [HW][5][128] bf16
    const float* __restrict__ lv,      // [HW]
    const u16* __restrict__ w2b, const float* __restrict__ b2e,
    const u16* __restrict__ w3b, const float* __restrict__ b3e,
    const float* __restrict__ x, float* __restrict__ outp)
{
  __shared__ __align__(16) u16 eAs[32][104];
  __shared__ __align__(16) u16 eBs[32][104];
  __shared__ float sAL[32], sBL[32];
  __shared__ __align__(16) u16 T2[32][136];
  const int t = threadIdx.x, lane = t & 63, w = t >> 6, jl = lane & 15, q = lane >> 4;
  const int rg = w & 1, ncl = w >> 1;
  const int i0 = blockIdx.x * 32;
  const int rowA = i0 + rg * 16 + jl;
  const int iloc = rg * 16 + jl;

  // ---- Phase A0: sep2a, once per row-group (ncl==0 waves)
  if (ncl == 0) {
    bf16x8 pfr[4];
#pragma unroll
    for (int l = 0; l < 4; ++l)
      pfr[l] = *(const bf16x8*)(pT + (size_t)rowA * 128 + l * 32 + q * 8);
    f32x4 sa[5], sb[5];
#pragma unroll
    for (int nf = 0; nf < 5; ++nf) {
      sa[nf] = (f32x4){0.f, 0.f, 0.f, 0.f};
      sb[nf] = (f32x4){0.f, 0.f, 0.f, 0.f};
    }
#pragma unroll
    for (int nf = 0; nf < 5; ++nf) {
      const int row = nf * 16 + jl;              // hj row, < 80
#pragma unroll
      for (int l = 0; l < 4; ++l) {
        bf16x8 eh = *(const bf16x8*)(efhT + (size_t)row * 128 + l * 32 + q * 8);
        bf16x8 ew = *(const bf16x8*)(efwT + (size_t)row * 128 + l * 32 + q * 8);
        sa[nf] = MFMA(eh, pfr[l], sa[nf]);
        sb[nf] = MFMA(ew, pfr[l], sb[nf]);
      }
    }
    float ra = 0.f, rb = 0.f;
#pragma unroll
    for (int nf = 0; nf < 5; ++nf) {
      float ea[4], eb[4];
#pragma unroll
      for (int r = 0; r < 4; ++r) {
        ea[r] = __expf(sa[nf][r]); ra += ea[r];
        eb[r] = __expf(sb[nf][r]); rb += eb[r];
      }
      uint2 pa, pb;
      pa.x = pack2(ea[0], ea[1]); pa.y = pack2(ea[2], ea[3]);
      pb.x = pack2(eb[0], eb[1]); pb.y = pack2(eb[2], eb[3]);
      *(uint2*)&eAs[iloc][nf * 16 + q * 4] = pa;
      *(uint2*)&eBs[iloc][nf * 16 + q * 4] = pb;
    }
    *(uint2*)&eAs[iloc][80 + q * 4] = (uint2){0u, 0u};
    *(uint2*)&eBs[iloc][80 + q * 4] = (uint2){0u, 0u};
    ra += __shfl_xor(ra, 16); ra += __shfl_xor(ra, 32);
    rb += __shfl_xor(rb, 16); rb += __shfl_xor(rb, 32);
    if (lane < 16) { sAL[iloc] = ra; sBL[iloc] = rb; }
  }
  __syncthreads();

  // ---- Phase A2: sep2b -> T2, once per row-group (ncl==1 waves)
  if (ncl == 1) {
    bf16x8 fa[3], fb[3];
#pragma unroll
    for (int l = 0; l < 3; ++l) {
      fa[l] = *(const bf16x8*)&eAs[iloc][l * 32 + q * 8];
      fb[l] = *(const bf16x8*)&eBs[iloc][l * 32 + q * 8];
    }
    f32x4 oU[8], oW[8];
#pragma unroll
    for (int nf = 0; nf < 8; ++nf) {
      oU[nf] = (f32x4){0.f, 0.f, 0.f, 0.f};
      oW[nf] = (f32x4){0.f, 0.f, 0.f, 0.f};
    }
#pragma unroll
    for (int l = 0; l < 3; ++l)
#pragma unroll
      for (int nf = 0; nf < 8; ++nf) {
        bf16x8 bh = *(const bf16x8*)(efhB + (size_t)(nf * 16 + jl) * 96 + l * 32 + q * 8);
        bf16x8 bw = *(const bf16x8*)(efwB + (size_t)(nf * 16 + jl) * 96 + l * 32 + q * 8);
        oU[nf] = MFMA(fa[l], bh, oU[nf]);
        oW[nf] = MFMA(fb[l], bw, oW[nf]);
      }
    float ia[4], iw[4];
#pragma unroll
    for (int r = 0; r < 4; ++r) {
      ia[r] = 1.0f / sAL[rg * 16 + q * 4 + r];
      iw[r] = 1.0f / sBL[rg * 16 + q * 4 + r];
    }
#pragma unroll
    for (int nf = 0; nf < 8; ++nf)
#pragma unroll
      for (int r = 0; r < 4; ++r)
        T2[rg * 16 + q * 4 + r][nf * 16 + jl] =
            f2b(oU[nf][r] * ia[r] + oW[nf][r] * iw[r]);
  }
  __syncthreads();

  // ---- Phase B: red (5 bf16 partials, contiguous) + output GEMMs
  const float inv1 = 1.0f / lv[rowA];
  const u16* OrBase = Opart + (size_t)rowA * 5 * 128;
  f32x4 a1[4], a2[4];
#pragma unroll
  for (int nf = 0; nf < 4; ++nf) {
    a1[nf] = (f32x4){0.f, 0.f, 0.f, 0.f};
    a2[nf] = (f32x4){0.f, 0.f, 0.f, 0.f};
  }
#pragma unroll
  for (int ks = 0; ks < 4; ++ks) {
    f32x4 s1a = (f32x4){0.f, 0.f, 0.f, 0.f};
    f32x4 s1b = (f32x4){0.f, 0.f, 0.f, 0.f};
#pragma unroll
    for (int p = 0; p < 5; ++p) {
      bf16x8 pv = *(const bf16x8*)(OrBase + p * 128 + ks * 32 + q * 8);
      f32x4 lo, hi;
      unpack8(pv, lo, hi);
      s1a += lo;
      s1b += hi;
    }
    bf16x8 fa1 = pack8(s1a, s1b, inv1);
    bf16x8 fa2 = *(const bf16x8*)&T2[rg * 16 + jl][ks * 32 + q * 8];
#pragma unroll
    for (int nf = 0; nf < 4; ++nf) {
      const int d = ncl * 64 + nf * 16 + jl;
      bf16x8 b2f = *(const bf16x8*)(w2b + (size_t)d * 128 + ks * 32 + q * 8);
      bf16x8 b3f = *(const bf16x8*)(w3b + (size_t)d * 128 + ks * 32 + q * 8);
      a1[nf] = MFMA(fa1, b2f, a1[nf]);
      a2[nf] = MFMA(fa2, b3f, a2[nf]);
    }
  }
#pragma unroll
  for (int nf = 0; nf < 4; ++nf) {
    const int d = ncl * 64 + nf * 16 + jl;
    const float bb2 = b2e[d], bb3 = b3e[d];
    const size_t base = (size_t)d * HW + i0 + rg * 16 + q * 4;
    f32x4 xv = *(const f32x4*)(x + base);
    f32x4 rv;
#pragma unroll
    for (int r = 0; r < 4; ++r)
      rv[r] = xv[r] + silu_f(a1[nf][r] + bb2) + silu_f(a2[nf][r] + bb3);
    *(f32x4*)(outp + base) = rv;
  }
}

// ---------------------------------------------------------------------------
extern "C" void kernel_launch(void* const* d_in, const int* in_sizes, int n_in,
                              void* d_out, int out_size, void* d_ws, size_t ws_size,
                              hipStream_t stream)
{
  (void)in_sizes; (void)n_in; (void)out_size; (void)ws_size;
  const float* x   = (const float*)d_in[0];
  const float* w1  = (const float*)d_in[1];
  const float* g1  = (const float*)d_in[2];
  const float* b1  = (const float*)d_in[3];
  const float* m1  = (const float*)d_in[4];
  const float* v1  = (const float*)d_in[5];
  const float* w2  = (const float*)d_in[6];
  const float* g2  = (const float*)d_in[7];
  const float* b2  = (const float*)d_in[8];
  const float* m2  = (const float*)d_in[9];
  const float* v2  = (const float*)d_in[10];
  const float* w3  = (const float*)d_in[11];
  const float* g3  = (const float*)d_in[12];
  const float* b3  = (const float*)d_in[13];
  const float* m3  = (const float*)d_in[14];
  const float* v3  = (const float*)d_in[15];
  const float* wq  = (const float*)d_in[16];
  const float* bq  = (const float*)d_in[17];
  const float* wk  = (const float*)d_in[18];
  const float* bk  = (const float*)d_in[19];
  const float* wv  = (const float*)d_in[20];
  const float* bv  = (const float*)d_in[21];
  const float* wp  = (const float*)d_in[22];
  const float* bp  = (const float*)d_in[23];
  const float* rel_h = (const float*)d_in[24];
  const float* rel_w = (const float*)d_in[25];
  const float* ef_h  = (const float*)d_in[26];
  const float* ef_w  = (const float*)d_in[27];
  float* outp = (float*)d_out;

  char* ws = (char*)d_ws;
  size_t off = 0;
  auto alloc = [&](size_t bytes) -> void* {
    void* p = ws + off;
    off += (bytes + 511) & ~(size_t)511;
    return p;
  };
  u16* LT    = (u16*)alloc((size_t)HW * 256 * 2);
  u16* RT    = (u16*)alloc((size_t)HW * 256 * 2);
  u16* pT    = (u16*)alloc((size_t)HW * 128 * 2);
  u16* Vv    = (u16*)alloc((size_t)HW * 128 * 2);
  u16* Opart = (u16*)alloc((size_t)HW * 5 * 128 * 2);      // 8.2 MB bf16
  float* lbuf  = (float*)alloc((size_t)HW * 4);
  u16* w1b   = (u16*)alloc(128 * 256 * 2);
  float* b1e = (float*)alloc(128 * 4);
  u16* Wcat  = (u16*)alloc(512 * 128 * 2);
  float* bcat = (float*)alloc(512 * 4);
  u16* w2b   = (u16*)alloc(256 * 128 * 2);
  float* b2e = (float*)alloc(256 * 4);
  u16* w3b   = (u16*)alloc(256 * 128 * 2);
  float* b3e = (float*)alloc(256 * 4);
  u16* efhT  = (u16*)alloc(80 * 128 * 2);
  u16* efwT  = (u16*)alloc(80 * 128 * 2);
  u16* efhB  = (u16*)alloc(128 * 96 * 2);
  u16* efwB  = (u16*)alloc(128 * 96 * 2);

  prep_all<<<176, 256, 0, stream>>>(rel_h, rel_w, ef_h, ef_w,
                                    w1, g1, b1, m1, v1, w2, g2, b2, m2, v2,
                                    w3, g3, b3, m3, v3, wq, bq, wk, bk, wv, bv, wp, bp,
                                    LT, w1b, b1e, Wcat, bcat, w2b, b2e, w3b, b3e,
                                    efhT, efwT, efhB, efwB, lbuf);
  front_k<<<800, 256, 0, stream>>>(x, w1b, b1e, Wcat, bcat, LT, RT, Vv, pT);
  fused_attn<<<250, 512, 0, stream>>>(LT, RT, Vv, Opart, lbuf);
  final2<<<dim3(200), 512, 0, stream>>>(pT, efhT, efwT, efhB, efwB,
                                        Opart, lbuf, w2b, b2e, w3b, b3e,
                                        x, outp);
}